// Round 13
// baseline (1131.744 us; speedup 1.0000x reference)
//
#include <hip/hip_runtime.h>

#define HH 256
#define WW 512
#define CPG 144
#define NKG 18                         // 144 ch = 18 groups of 8
#define WP 516                         // 512 + 2 left + 2 right
#define HPADR 258                      // 256 + 2 top halo rows
#define XB_E ((size_t)NKG * HPADR * WP * 8)   // 19170432 elems per activation buffer
#define NCH 59                         // K-chunks of 32 (K = 13*144 = 1872)
#define KREAL 1872
#define SCALE_F (2.0f / 47.0f)

typedef __attribute__((ext_vector_type(8))) short short8;
typedef __attribute__((ext_vector_type(4))) float floatx4;

__device__ __forceinline__ unsigned short f2bf(float f) {
    unsigned u = __builtin_bit_cast(unsigned, f);
    u += 0x7FFFu + ((u >> 16) & 1u);
    return (unsigned short)(u >> 16);
}
__device__ __forceinline__ float bf2f(unsigned short h) {
    unsigned u = ((unsigned)h) << 16;
    return __builtin_bit_cast(float, u);
}
__device__ __forceinline__ void async16(const void* g, void* l) {
    __builtin_amdgcn_global_load_lds(
        (const __attribute__((address_space(1))) unsigned int*)g,
        (__attribute__((address_space(3))) unsigned int*)l, 16, 0, 0);
}
// mask-B taps t=0..12: kh = t<5?0:(t<10?1:2), kw = t - {0,5,10}
__device__ __forceinline__ void tap_decode(int t, int& kh, int& kw) {
    kh = t < 5 ? 0 : (t < 10 ? 1 : 2);
    kw = t - (t < 5 ? 0 : (t < 10 ? 5 : 10));
}
// LDS byte offset (within 6-row window, excluding r/lr/m terms) of chunk c, lg
__device__ __forceinline__ unsigned aoff6(int c, int lg) {
    int g = c * 4 + lg;                // 8-ch group index
    if (g > 233) g = 233;              // pad K: weights are 0 there
    int t = (g * 57) >> 10;            // g/18, exact for g<=233
    int kgp = g - t * 18;
    int kh, kw; tap_decode(t, kh, kw);
    return (unsigned)(((kgp * 6 + kh) * 68 + kw) * 16);
}

// ---------------- zero workspace ------------------------------------------
__global__ void k_zero(float* __restrict__ p, size_t n4) {
    size_t i = (size_t)blockIdx.x * blockDim.x + threadIdx.x;
    size_t stride = (size_t)gridDim.x * blockDim.x;
    float4 z = make_float4(0.f, 0.f, 0.f, 0.f);
    for (; i < n4; i += stride) ((float4*)p)[i] = z;
}

// ---------------- weight packing ------------------------------------------
// hidden: wpk[l][c][lg4][co144][j8], K = c*32 + lg*8 + j  (LDS-ready layout)
__global__ void k_pack_hidden(const float* __restrict__ wres, unsigned short* __restrict__ wpk) {
    const int total = 10 * NCH * 4 * CPG * 8;
    int i = blockIdx.x * blockDim.x + threadIdx.x;
    int stride = gridDim.x * blockDim.x;
    for (; i < total; i += stride) {
        int j  = i & 7;
        int q  = i >> 3;
        int co = q % CPG;  q /= CPG;
        int lg = q & 3;    q >>= 2;
        int c  = q % NCH;
        int l  = q / NCH;
        int K = c * 32 + lg * 8 + j;
        float v = 0.f;
        if (K < KREAL) {
            int t = K / CPG, ci = K - t * CPG;
            int kh, kw; tap_decode(t, kh, kw);
            v = wres[(((size_t)(l * CPG + co) * CPG + ci) * 5 + kh) * 5 + kw];
        }
        wpk[i] = f2bf(v);
    }
}
// final: wpkF[c][lg4][co64][j8] (co>=49 zero)
__global__ void k_pack_final(const float* __restrict__ wl, unsigned short* __restrict__ wpkF) {
    const int total = NCH * 4 * 64 * 8;
    int i = blockIdx.x * blockDim.x + threadIdx.x;
    if (i >= total) return;
    int j  = i & 7;
    int co = (i >> 3) & 63;
    int lg = (i >> 9) & 3;
    int c  = i >> 11;
    int K = c * 32 + lg * 8 + j;
    float v = 0.f;
    if (K < KREAL && co < 49) {
        int t = K / CPG, ci = K - t * CPG;
        int kh, kw; tap_decode(t, kh, kw);
        v = wl[(((size_t)co * CPG + ci) * 5 + kh) * 5 + kw];
    }
    wpkF[i] = f2bf(v);
}
// small: w0p[t*144+co] fp32 (12 mask-A taps) + blp[64] (bias pad)
__global__ void k_pack_small(const float* __restrict__ w0, const float* __restrict__ bl,
                             float* __restrict__ w0p, float* __restrict__ blp) {
    int i = blockIdx.x * blockDim.x + threadIdx.x;
    if (i < 12 * CPG) {
        int co = i % CPG, t = i / CPG;
        int kh, kw; tap_decode(t, kh, kw);   // t<12: mask-A (row2 only kw 0,1)
        w0p[i] = w0[co * 25 + kh * 5 + kw];
    } else if (i < 12 * CPG + 64) {
        int k = i - 12 * CPG;
        blp[k] = k < 49 ? bl[k] : 0.f;
    }
}

// ---------------- layer 0: data -> Xb bf16 blocked [kg][y][x][8] ----------
__global__ __launch_bounds__(384) void k_layer0(
    const float* __restrict__ data, const float* __restrict__ w0p,
    const float* __restrict__ b0, unsigned short* __restrict__ Xb) {
    const int lane = threadIdx.x;                 // 0..63
    const int x = blockIdx.x * 64 + lane;
    const int y = blockIdx.y;

    float xv[12];
#pragma unroll
    for (int t = 0; t < 12; t++) {
        int kh, kw; tap_decode(t, kh, kw);
        int yy = y + kh - 2, xx = x + kw - 2;
        xv[t] = (yy >= 0 && xx >= 0 && xx < WW) ? data[yy * WW + xx] * SCALE_F - 1.0f : 0.f;
    }
#pragma unroll
    for (int kgi = 0; kgi < 3; kgi++) {
        int kg = threadIdx.y * 3 + kgi;           // 0..17
        float a8[8];
#pragma unroll
        for (int j = 0; j < 8; j++) a8[j] = 0.f;
#pragma unroll
        for (int t = 0; t < 12; t++)
#pragma unroll
            for (int j = 0; j < 8; j++)
                a8[j] = fmaf(w0p[t * CPG + kg * 8 + j], xv[t], a8[j]);
        short8 o;
#pragma unroll
        for (int j = 0; j < 8; j++)
            o[j] = (short)f2bf(fmaxf(a8[j] + b0[kg * 8 + j], 0.f));
        *(short8*)&Xb[((size_t)(kg * HPADR + y + 2) * WP + (x + 2)) * 8] = o;
    }
}

// ---------------- hidden conv: phase-locked LDS pipeline (T3/T4) ----------
// block = 64px x 4 out rows x 144 co; 12 waves = ng(3) x r(4); wave tile
// 64px x 48co (Mf=4 x Nf=3) = 12 MFMA per (4 A-ds_b128 + 3 B-ds_b128).
// A: persistent 6-row x 68-px x 144-ch window (117.5 KB), staged once.
// B: 3-deep LDS ring (27.6 KB), staged per-chunk via 9 gll (waves 0-8,
// <=1 per wave) with counted vmcnt(1) -- never drained to 0 in the loop.
template<bool RES>
__global__ __launch_bounds__(768, 3) void k_conv(
    const unsigned short* __restrict__ in,
    const unsigned short* __restrict__ wq,
    const float* __restrict__ bias,
    const unsigned short* __restrict__ res,
    unsigned short* __restrict__ out) {
    __shared__ __align__(16) unsigned short As[NKG][6][68][8];   // 117504 B
    __shared__ __align__(16) unsigned short Bs[3][4608];         // 27648 B
    const int tid  = threadIdx.x;
    const int lane = tid & 63;
    const int wid  = tid >> 6;          // 0..11
    const int ng   = wid % 3;           // co-group of 48
    const int r    = wid / 3;           // output row 0..3
    const int lr = lane & 15;
    const int lg = lane >> 4;

    // XCD-chunked swizzle: 512 blocks -> 64 consecutive per XCD
    const int fid = blockIdx.x + (int)gridDim.x * blockIdx.y;   // 0..511
    const int swz = (fid & 7) * 64 + (fid >> 3);
    const int x0 = (swz & 7) * 64;      // padded-col base (8 x-tiles)
    const int y0 = (swz >> 3) * 4;      // padded-row base (64 y-tiles)

    floatx4 acc[4][3];
#pragma unroll
    for (int m = 0; m < 4; m++)
#pragma unroll
        for (int n = 0; n < 3; n++) acc[m][n] = (floatx4)0.f;

    // ---- prologue: A window (108 gll + halo) + B(0),B(1); one drain ----
    for (int i = wid; i < 108; i += 12) {        // kg(18) x row(6)
        int kg = i / 6, rr = i - (i / 6) * 6;
        async16(in + ((size_t)(kg * HPADR + y0 + rr) * WP + x0 + lane) * 8,
                &As[kg][rr][0][0]);
    }
    if (tid < 432) {                    // halo px 64..67, all 6 rows
        int kg = tid / 24;
        int rem = tid - kg * 24;
        int rr = rem >> 2;
        int p  = rem & 3;
        *(short8*)&As[kg][rr][64 + p][0] =
            *(const short8*)(in + ((size_t)(kg * HPADR + y0 + rr) * WP + x0 + 64 + p) * 8);
    }
    for (int i = wid; i < 18; i += 12) {         // B chunks 0,1 (9 gll each)
        int c = i / 9, s = i - (i / 9) * 9;
        async16(wq + (size_t)c * 4608 + s * 512 + lane * 8, &Bs[c][s * 512]);
    }
    asm volatile("s_waitcnt vmcnt(0) lgkmcnt(0)" ::: "memory");
    __builtin_amdgcn_s_barrier();
    __builtin_amdgcn_sched_barrier(0);

    const char* abase = (const char*)As + ((r * 68) + lr) * 16;
    int bufR = 0, bufW = 2;             // read ring slot, write ring slot
#pragma unroll 1
    for (int c = 0; c < NCH; ++c) {
        // stage B(c+2) -> ring slot bufW (waves 0-8, one gll each)
        if (wid < 9 && c + 2 < NCH)
            async16(wq + (size_t)(c + 2) * 4608 + wid * 512 + lane * 8,
                    &Bs[bufW][wid * 512]);
        // ds reads for chunk c
        short8 a[4], b[3];
        const char* ap = abase + aoff6(c, lg);
#pragma unroll
        for (int m = 0; m < 4; ++m) a[m] = *(const short8*)(ap + m * 256);
        const unsigned short* bb = &Bs[bufR][lg * 1152 + (ng * 48 + lr) * 8];
#pragma unroll
        for (int n = 0; n < 3; ++n) b[n] = *(const short8*)(bb + n * 128);
        // MFMA cluster (compiler inserts lgkmcnt before first use)
        __builtin_amdgcn_s_setprio(1);
#pragma unroll
        for (int m = 0; m < 4; ++m)
#pragma unroll
            for (int n = 0; n < 3; ++n)
                acc[m][n] = __builtin_amdgcn_mfma_f32_16x16x32_bf16(a[m], b[n], acc[m][n], 0, 0, 0);
        __builtin_amdgcn_s_setprio(0);
        __builtin_amdgcn_sched_barrier(0);
        // counted wait: own newest gll (c+2) may stay in flight; (c+1) must land
        asm volatile("s_waitcnt vmcnt(1)" ::: "memory");
        __builtin_amdgcn_s_barrier();
        __builtin_amdgcn_sched_barrier(0);
        bufR = bufR == 2 ? 0 : bufR + 1;
        bufW = bufW == 2 ? 0 : bufW + 1;
    }

    // ---- epilogue ----
#pragma unroll
    for (int n = 0; n < 3; ++n) {
        int co = ng * 48 + n * 16 + lr;
        float bv = bias[co];
        const size_t pb = ((size_t)((co >> 3) * HPADR + y0 + 2 + r) * WP + (x0 + 2)) * 8 + (co & 7);
#pragma unroll
        for (int m = 0; m < 4; ++m)
#pragma unroll
            for (int rr = 0; rr < 4; ++rr) {
                int px = m * 16 + lg * 4 + rr;
                size_t o = pb + (size_t)px * 8;
                float v = fmaxf(acc[m][n][rr] + bv, 0.f);
                if (RES) v += bf2f(res[o]);
                out[o] = f2bf(v);
            }
    }
}

// ---------------- final conv (144 -> 49 pad 64): same phase pipeline ------
// 8 waves = ng(2) x r(4); wave tile 64px x 32co (Mf=4 x Nf=2).
__global__ __launch_bounds__(512, 2) void k_logits(
    const unsigned short* __restrict__ in,
    const unsigned short* __restrict__ wq,
    const float* __restrict__ blp,
    float* __restrict__ logits) {
    __shared__ __align__(16) unsigned short As[NKG][6][68][8];   // 117504 B
    __shared__ __align__(16) unsigned short Bs[3][2048];         // 12288 B
    const int tid  = threadIdx.x;
    const int lane = tid & 63;
    const int wid  = tid >> 6;          // 0..7
    const int ng   = wid & 1;           // co-group of 32
    const int r    = wid >> 1;          // output row 0..3
    const int lr = lane & 15;
    const int lg = lane >> 4;

    const int fid = blockIdx.x + (int)gridDim.x * blockIdx.y;   // 0..511
    const int swz = (fid & 7) * 64 + (fid >> 3);
    const int x0 = (swz & 7) * 64;
    const int y0 = (swz >> 3) * 4;

    floatx4 acc[4][2];
#pragma unroll
    for (int m = 0; m < 4; m++)
#pragma unroll
        for (int n = 0; n < 2; n++) acc[m][n] = (floatx4)0.f;

    for (int i = wid; i < 108; i += 8) {
        int kg = i / 6, rr = i - (i / 6) * 6;
        async16(in + ((size_t)(kg * HPADR + y0 + rr) * WP + x0 + lane) * 8,
                &As[kg][rr][0][0]);
    }
    if (tid < 432) {
        int kg = tid / 24;
        int rem = tid - kg * 24;
        int rr = rem >> 2;
        int p  = rem & 3;
        *(short8*)&As[kg][rr][64 + p][0] =
            *(const short8*)(in + ((size_t)(kg * HPADR + y0 + rr) * WP + x0 + 64 + p) * 8);
    }
    for (int i = wid; i < 8; i += 8) {           // B chunks 0,1 (4 gll each)
        int c = i >> 2, s = i & 3;
        async16(wq + (size_t)c * 2048 + s * 512 + lane * 8, &Bs[c][s * 512]);
    }
    asm volatile("s_waitcnt vmcnt(0) lgkmcnt(0)" ::: "memory");
    __builtin_amdgcn_s_barrier();
    __builtin_amdgcn_sched_barrier(0);

    const char* abase = (const char*)As + ((r * 68) + lr) * 16;
    int bufR = 0, bufW = 2;
#pragma unroll 1
    for (int c = 0; c < NCH; ++c) {
        if (wid < 4 && c + 2 < NCH)
            async16(wq + (size_t)(c + 2) * 2048 + wid * 512 + lane * 8,
                    &Bs[bufW][wid * 512]);
        short8 a[4], b[2];
        const char* ap = abase + aoff6(c, lg);
#pragma unroll
        for (int m = 0; m < 4; ++m) a[m] = *(const short8*)(ap + m * 256);
        const unsigned short* bb = &Bs[bufR][lg * 512 + (ng * 32 + lr) * 8];
#pragma unroll
        for (int n = 0; n < 2; ++n) b[n] = *(const short8*)(bb + n * 128);
        __builtin_amdgcn_s_setprio(1);
#pragma unroll
        for (int m = 0; m < 4; ++m)
#pragma unroll
            for (int n = 0; n < 2; ++n)
                acc[m][n] = __builtin_amdgcn_mfma_f32_16x16x32_bf16(a[m], b[n], acc[m][n], 0, 0, 0);
        __builtin_amdgcn_s_setprio(0);
        __builtin_amdgcn_sched_barrier(0);
        asm volatile("s_waitcnt vmcnt(1)" ::: "memory");
        __builtin_amdgcn_s_barrier();
        __builtin_amdgcn_sched_barrier(0);
        bufR = bufR == 2 ? 0 : bufR + 1;
        bufW = bufW == 2 ? 0 : bufW + 1;
    }

#pragma unroll
    for (int n = 0; n < 2; ++n) {
        int co = ng * 32 + n * 16 + lr;
        float bv = blp[co];
#pragma unroll
        for (int m = 0; m < 4; ++m)
#pragma unroll
            for (int rr = 0; rr < 4; ++rr) {
                int px = m * 16 + lg * 4 + rr;
                logits[((size_t)(y0 + r) * WW + x0 + px) * 64 + co] = acc[m][n][rr] + bv;
            }
    }
}

// ---------------- softmax + cdf -> d_out ----------------------------------
__global__ __launch_bounds__(256) void k_softmax(
    const float* __restrict__ lg, float* __restrict__ out) {
    const int px = blockIdx.x * 256 + threadIdx.x;
    const int y = blockIdx.y;
    const size_t p = (size_t)y * WW + px;
    const float* l = lg + p * 64;
    float v[49];
    float m = -1e30f;
#pragma unroll
    for (int k = 0; k < 49; k++) { v[k] = l[k]; m = fmaxf(m, v[k]); }
    float s = 0.f;
#pragma unroll
    for (int k = 0; k < 49; k++) {
        v[k] = exp2f((v[k] - m) * 1.44269504088896f);
        s += v[k];
    }
    const float inv = 65536.0f / s;
    out[p] = 0.f;
    float run = 0.f;
#pragma unroll
    for (int k = 0; k < 49; k++) {
        run += v[k];
        out[(size_t)(k + 1) * (HH * WW) + p] = run * inv;
    }
}

// ---------------- launcher -------------------------------------------------
extern "C" void kernel_launch(void* const* d_in, const int* in_sizes, int n_in,
                              void* d_out, int out_size, void* d_ws, size_t ws_size,
                              hipStream_t stream) {
    (void)in_sizes; (void)n_in; (void)out_size; (void)ws_size;
    const float* data = (const float*)d_in[0];
    const float* w0   = (const float*)d_in[1];
    const float* b0   = (const float*)d_in[2];
    const float* wres = (const float*)d_in[3];
    const float* bres = (const float*)d_in[4];
    const float* wl   = (const float*)d_in[5];
    const float* bl   = (const float*)d_in[6];
    float* out = (float*)d_out;

    char* ws = (char*)d_ws;
    unsigned short* Xb   = (unsigned short*)ws;                 // 19170432 elems
    unsigned short* Hb   = Xb + XB_E;                           // 19170432
    unsigned short* wpk  = Hb + XB_E;                           // 10*59*4*144*8 = 2718720
    unsigned short* wpkF = wpk + (size_t)10 * NCH * 4 * CPG * 8;// 59*4*64*8 = 120832
    float* blp  = (float*)(wpkF + (size_t)NCH * 4 * 64 * 8);    // 64
    float* w0p  = blp + 64;                                     // 1728
    float* logits = w0p + 1728;                                 // 131072*64 fp32

    // zero both activation buffers (halos must be 0; ws is poisoned)
    k_zero<<<2048, 256, 0, stream>>>((float*)ws, (2 * XB_E * 2) / 16);

    k_pack_hidden<<<2048, 256, 0, stream>>>(wres, wpk);
    k_pack_final<<<(NCH * 4 * 64 * 8 + 255) / 256, 256, 0, stream>>>(wl, wpkF);
    k_pack_small<<<7, 256, 0, stream>>>(w0, bl, w0p, blp);

    k_layer0<<<dim3(8, 256), dim3(64, 6), 0, stream>>>(data, w0p, b0, Xb);

    const size_t LSTRIDE = (size_t)NCH * 4 * CPG * 8;   // 271872 shorts/layer
    for (int i = 0; i < 5; i++) {
        k_conv<false><<<dim3(8, 64), 768, 0, stream>>>(
            Xb, wpk + (size_t)(2 * i) * LSTRIDE, bres + (2 * i) * CPG, Xb, Hb);
        k_conv<true><<<dim3(8, 64), 768, 0, stream>>>(
            Hb, wpk + (size_t)(2 * i + 1) * LSTRIDE, bres + (2 * i + 1) * CPG, Xb, Xb);
    }

    k_logits<<<dim3(8, 64), 512, 0, stream>>>(Xb, wpkF, blp, logits);
    k_softmax<<<dim3(2, 256), 256, 0, stream>>>(logits, out);
}